// Round 6
// baseline (166.496 us; speedup 1.0000x reference)
//
#include <hip/hip_runtime.h>

// SNN "SynapticChain": B=4, T=24, N=4096, F=32, L=3 (+1 final synaptic layer).
// Wave64 = 2 rows (32 lanes/row, lane l = feature index). T-loop in kernel.
// Chain/lin matmuls: binary spikes -> per-block 4-bit LUT in LDS (unchanged).
// R6: MLP broadcasts moved OFF the LDS pipe: DPP row_ror systolic rotation
//     (VALU pipe) within 16-lane rows + one ds_swizzle xor16 per cross-half
//     partial. R5 model: LDS pipe was saturated (470 cy/wave-t = 150us = dur);
//     MLP b128 broadcasts were 288 cy of it. Rotation direction is probed at
//     runtime and absorbed into the weight-register layout (direction-safe).

namespace {
constexpr int kB = 4;
constexpr int kT = 24;
constexpr int kN = 4096;
constexpr int kF = 32;
constexpr int kNF = kN * kF;

__device__ __forceinline__ float dpp_ror(float x, int /*unused*/) { return x; }

template<int S>
__device__ __forceinline__ float ror16(float x) {
    static_assert(S >= 1 && S <= 15, "row_ror range");
    return __int_as_float(__builtin_amdgcn_update_dpp(
        0, __float_as_int(x), 0x120 | S, 0xF, 0xF, true));
}

__device__ __forceinline__ float swz_x16(float x) {
    // ds_swizzle bitmode: and=0x1F, or=0, xor=0x10 -> lane ^ 16 within 32-half
    return __int_as_float(__builtin_amdgcn_ds_swizzle(__float_as_int(x), 0x401F));
}

// MLP1: rotate t; 4 accumulators (own h1[l], own h1[l+32], partner's pair)
template<int S>
__device__ __forceinline__ void mlp1_steps(float tv,
        const float* w_oa, const float* w_ob,
        const float* w_xa, const float* w_xb,
        float& oa, float& ob, float& xa, float& xb) {
    if constexpr (S <= 15) {
        float v;
        if constexpr (S == 0) v = tv; else v = ror16<S>(tv);
        oa = fmaf(v, w_oa[S], oa);
        ob = fmaf(v, w_ob[S], ob);
        xa = fmaf(v, w_xa[S], xa);
        xb = fmaf(v, w_xb[S], xb);
        mlp1_steps<S + 1>(tv, w_oa, w_ob, w_xa, w_xb, oa, ob, xa, xb);
    }
}

// MLP2: rotate (g1,g2); 2 accumulators (own out[l], partner out[l^16])
template<int S>
__device__ __forceinline__ void mlp2_steps(float u0, float u1,
        const float* w_o0, const float* w_o1,
        const float* w_x0, const float* w_x1,
        float& oo, float& xx) {
    if constexpr (S <= 15) {
        float v0, v1;
        if constexpr (S == 0) { v0 = u0; v1 = u1; }
        else { v0 = ror16<S>(u0); v1 = ror16<S>(u1); }
        oo = fmaf(v0, w_o0[S], oo);
        oo = fmaf(v1, w_o1[S], oo);
        xx = fmaf(v0, w_x0[S], xx);
        xx = fmaf(v1, w_x1[S], xx);
        mlp2_steps<S + 1>(u0, u1, w_o0, w_o1, w_x0, w_x1, oo, xx);
    }
}

__global__ __launch_bounds__(512, 2)
void snn_fused(const float* __restrict__ x,
               const float* __restrict__ alphas,
               const float* __restrict__ betas,
               const float* __restrict__ thrs,
               const float* __restrict__ chain_W,
               const float* __restrict__ chain_b,
               const float* __restrict__ lin_W,
               const float* __restrict__ lin_b,
               const float* __restrict__ W1,
               const float* __restrict__ b1,
               const float* __restrict__ prelu_a,
               const float* __restrict__ W2,
               const float* __restrict__ b2,
               float* __restrict__ out)
{
    const int tid  = threadIdx.x;
    const int lane = tid & 63;
    const int half = lane >> 5;        // row within the wave
    const int l    = lane & 31;        // feature / output index within row
    const int l16  = lane & 15;        // index within DPP 16-row
    const int gbase= l & 16;           // which 16-group of the 32 (0 or 16)
    const int wid  = tid >> 6;         // wave id in block (0..7)
    const int row  = blockIdx.x * 16 + wid * 2 + half;  // 0..16383
    const int b    = row >> 12;
    const int n    = row & (kN - 1);

    // ---- LDS: nibble LUT only (64 KB)
    __shared__ float lut[4][8][16][32];   // [mat][group][nib][j]

    // ---- LUT init: 1024 (mat,g,j) combos, 2 per thread; 16 nibble sums each
#pragma unroll
    for (int c = 0; c < 2; ++c) {
        const int idx = tid + c * 512;
        const int mat = idx >> 8;          // 0..3
        const int g   = (idx >> 5) & 7;    // 0..7
        const int jj  = idx & 31;          // 0..31
        const float* wsrc = (mat < 3) ? (chain_W + ((mat * kF + jj) * kF + g * 4))
                                      : (lin_W + (jj * kF + g * 4));
        const float4 w = *reinterpret_cast<const float4*>(wsrc);
        const float bias = (g == 0) ? ((mat < 3) ? chain_b[mat * kF + jj] : lin_b[jj])
                                    : 0.0f;
        float s[16];
        s[0]  = 0.0f;
        s[1]  = w.x;         s[2]  = w.y;         s[3]  = w.x + w.y;
        s[4]  = w.z;         s[5]  = w.x + w.z;   s[6]  = w.y + w.z;
        s[7]  = s[3] + w.z;  s[8]  = w.w;         s[9]  = w.x + w.w;
        s[10] = w.y + w.w;   s[11] = s[3] + w.w;  s[12] = w.z + w.w;
        s[13] = s[5] + w.w;  s[14] = s[6] + w.w;  s[15] = s[7] + w.w;
#pragma unroll
        for (int nb = 0; nb < 16; ++nb) lut[mat][g][nb][jj] = s[nb] + bias;
    }
    __syncthreads();

    // ---- uniform scalars
    float al[4], be[4], th[4];
#pragma unroll
    for (int i = 0; i < 4; ++i) {
        al[i] = fminf(fmaxf(alphas[i], 0.0f), 1.0f);
        be[i] = fminf(fmaxf(betas[i],  0.0f), 1.0f);
        th[i] = thrs[i];
    }
    const float pa = prelu_a[0];

    // ---- DPP row_ror direction probe: lane0 receives lane1 (d=+1) or lane15
    const int pr = __builtin_amdgcn_update_dpp(0, lane, 0x121, 0xF, 0xF, true);
    const int d  = (__builtin_amdgcn_readfirstlane(pr) == 1) ? 1 : 15;

    // ---- MLP weights in rotation order (direction absorbed here)
    const int lx = l ^ 16;
    float w1_oa[16], w1_ob[16], w1_xa[16], w1_xb[16];
    float w2_o0[16], w2_o1[16], w2_x0[16], w2_x1[16];
#pragma unroll
    for (int s = 0; s < 16; ++s) {
        const int idx = ((l16 + d * s) & 15) | gbase;   // input index seen at step s
        w1_oa[s] = W1[l         * kF + idx];
        w1_ob[s] = W1[(l + 32)  * kF + idx];
        w1_xa[s] = W1[lx        * kF + idx];
        w1_xb[s] = W1[(lx + 32) * kF + idx];
        w2_o0[s] = W2[l  * 64 + idx];
        w2_o1[s] = W2[l  * 64 + idx + 32];
        w2_x0[s] = W2[lx * 64 + idx];
        w2_x1[s] = W2[lx * 64 + idx + 32];
    }
    const float b1a = b1[l];
    const float b1b = b1[l + 32];
    const float ob  = b2[l];

    float syn[4] = {0.f, 0.f, 0.f, 0.f};
    float mem[4] = {0.f, 0.f, 0.f, 0.f};

    const float* xp = x   + (b * kT * kN + n) * kF + l;
    float*       op = out + (b * kT * kN + n) * kF + l;

    float xv = xp[0];                      // prefetched x for current t

    for (int t = 0; t < kT; ++t) {
        float xnext = 0.0f;
        if (t + 1 < kT) xnext = xp[(t + 1) * kNF];

        float h = xv;
        float transformed = 0.0f;

#pragma unroll
        for (int i = 0; i < 4; ++i) {
            // synaptic_step (reset from PREVIOUS mem, detached)
            const float mo    = mem[i];
            const float reset = ((mo - th[i]) > 0.0f) ? 1.0f : 0.0f;
            syn[i] = al[i] * syn[i] + h;
            mem[i] = be[i] * mem[i] + syn[i] - reset * th[i];
            const bool sp = (mem[i] - th[i]) > 0.0f;

            const unsigned long long m64 = __ballot(sp);
            const unsigned m32 = half ? (unsigned)(m64 >> 32) : (unsigned)m64;

            // binary matmul via nibble LUT (bias folded into g=0)
            float v[8];
#pragma unroll
            for (int g = 0; g < 8; ++g) {
                const unsigned nib = (m32 >> (4 * g)) & 15u;
                v[g] = lut[i][g][nib][l];
            }
            const float acc = ((v[0] + v[1]) + (v[2] + v[3]))
                            + ((v[4] + v[5]) + (v[6] + v[7]));
            if (i < 3) h = acc; else transformed = acc;
        }

        // ---- MLP1: 32 -> 64 via DPP systolic (no LDS broadcast)
        float oa = b1a, obv = b1b, xa = 0.0f, xb = 0.0f;
        mlp1_steps<0>(transformed, w1_oa, w1_ob, w1_xa, w1_xb, oa, obv, xa, xb);
        const float h1a = oa  + swz_x16(xa);
        const float h1b = obv + swz_x16(xb);
        const float g1 = (h1a > 0.0f) ? h1a : pa * h1a;
        const float g2 = (h1b > 0.0f) ? h1b : pa * h1b;

        // ---- MLP2: 64 -> 32 via DPP systolic
        float oo = ob, xx = 0.0f;
        mlp2_steps<0>(g1, g2, w2_o0, w2_o1, w2_x0, w2_x1, oo, xx);
        op[t * kNF] = oo + swz_x16(xx);

        xv = xnext;
    }
}
} // namespace

extern "C" void kernel_launch(void* const* d_in, const int* in_sizes, int n_in,
                              void* d_out, int out_size, void* d_ws, size_t ws_size,
                              hipStream_t stream) {
    const float* x        = (const float*)d_in[0];
    const float* alphas   = (const float*)d_in[1];
    const float* betas    = (const float*)d_in[2];
    const float* thrs     = (const float*)d_in[3];
    const float* chain_W  = (const float*)d_in[4];
    const float* chain_b  = (const float*)d_in[5];
    const float* lin_W    = (const float*)d_in[6];
    const float* lin_b    = (const float*)d_in[7];
    const float* W1       = (const float*)d_in[8];
    const float* b1       = (const float*)d_in[9];
    const float* prelu_a  = (const float*)d_in[10];
    const float* W2       = (const float*)d_in[11];
    const float* b2       = (const float*)d_in[12];
    float* out            = (float*)d_out;

    const int rows   = kB * kN;          // 16384
    const int blocks = rows / 16;        // 1024 blocks * 8 waves * 2 rows/wave
    hipLaunchKernelGGL(snn_fused, dim3(blocks), dim3(512), 0, stream,
                       x, alphas, betas, thrs, chain_W, chain_b, lin_W, lin_b,
                       W1, b1, prelu_a, W2, b2, out);
}